// Round 6
// baseline (1249.036 us; speedup 1.0000x reference)
//
#include <hip/hip_runtime.h>

#define T_ 128
#define B_ 128
#define C_ 128
#define N_ 10
#define V_ 5
#define XROW 1280            // C_*N_ elems per (t,b)
#define ZROW 640             // C_*V_ per (t,b)
#define ZSTRIDE 81920        // B_*C_*V_ per t
#define XSTRIDE 163840       // B_*C_*N_ per t

// ---------------------------------------------------------------------------
// k_prep: W1 -> W1T[c][o] f32 (64KB) ; Wf -> WfT[c2][o] f32 (128KB)
// ---------------------------------------------------------------------------
__global__ __launch_bounds__(256) void k_prep(const float* __restrict__ W1,
                                              const float* __restrict__ Wf,
                                              float* __restrict__ W1T,
                                              float* __restrict__ WfT) {
  int i = blockIdx.x * 256 + threadIdx.x;      // 49152 threads
  if (i < 16384) {
    int c = i >> 7, o = i & 127;
    W1T[i] = W1[o * 128 + c];
  } else if (i < 49152) {
    int k = i - 16384;
    int c2 = k >> 7, o = k & 127;
    WfT[k] = Wf[o * 256 + c2];
  }
}

// ---------------------------------------------------------------------------
// k_xconv: x chunk f32 -> x_d f64 (exact widening)
// ---------------------------------------------------------------------------
__global__ __launch_bounds__(256) void k_xconv(const float* __restrict__ x,
                                               double* __restrict__ xd,
                                               long long base_elem) {
  long long i = (long long)blockIdx.x * 256 + threadIdx.x;   // PQ*640 threads
  float2 v = *(const float2*)(x + base_elem + 2 * i);
  double2 d; d.x = (double)v.x; d.y = (double)v.y;
  *(double2*)(xd + 2 * i) = d;
}

// ---------------------------------------------------------------------------
// k_gemm1: y_buf[pl][o][n] = GN8( W1 @ x ) fp64, one t-chunk.
// 512 thr = 4 groups x 128 o; 4 pairs/group -> 16 pairs/block.
// Weights: f32 LDS (staged once, cvt per c). x_d: wave-uniform f64 s_loads.
// ---------------------------------------------------------------------------
__global__ __launch_bounds__(512) void k_gemm1(
    const double* __restrict__ x_d, const float* __restrict__ W1T,
    const float* __restrict__ g1, const float* __restrict__ b1,
    double* __restrict__ y_buf)
{
  __shared__ float w1t[16384];                 // [c][o], 64 KB
  const int tid = threadIdx.x;
  const int o   = tid & 127;
  const int grp = tid >> 7;                    // 0..3
  const int pl0 = blockIdx.x * 16 + grp * 4;   // chunk-local pair base

  for (int i = tid; i < 16384; i += 512) w1t[i] = W1T[i];
  __syncthreads();

  int xb[4];
#pragma unroll
  for (int k = 0; k < 4; ++k)
    xb[k] = __builtin_amdgcn_readfirstlane((pl0 + k) * XROW);

  double acc[4][10];
#pragma unroll
  for (int k = 0; k < 4; ++k)
#pragma unroll
    for (int j = 0; j < 10; ++j) acc[k][j] = 0.0;

#pragma unroll 2
  for (int c = 0; c < 128; ++c) {
    const double w = (double)w1t[(c << 7) + o];   // lossless f32->f64
#pragma unroll
    for (int k = 0; k < 4; ++k) {
      const double* xp = x_d + xb[k] + c * 10;
#pragma unroll
      for (int j = 0; j < 10; ++j)
        acc[k][j] = fma(w, xp[j], acc[k][j]);
    }
  }

  // GN8: group = (o>>4), 16 lanes x 10 = 160 elems, in-wave tree
  const double gam = (double)g1[o], bet = (double)b1[o];
#pragma unroll
  for (int k = 0; k < 4; ++k) {
    double s = 0.0;
#pragma unroll
    for (int j = 0; j < 10; ++j) s += acc[k][j];
#pragma unroll
    for (int off = 1; off < 16; off <<= 1) s += __shfl_xor(s, off, 64);
    const double mu = s * (1.0 / 160.0);
    double sq = 0.0;
#pragma unroll
    for (int j = 0; j < 10; ++j) { double d = acc[k][j] - mu; sq = fma(d, d, sq); }
#pragma unroll
    for (int off = 1; off < 16; off <<= 1) sq += __shfl_xor(sq, off, 64);
    const double rstd = 1.0 / sqrt(sq * (1.0 / 160.0) + 1e-5);
    double* yo = y_buf + (size_t)(pl0 + k) * XROW + o * 10;
#pragma unroll
    for (int j = 0; j < 10; ++j) yo[j] = (acc[k][j] - mu) * rstd * gam + bet;
  }
}

// ---------------------------------------------------------------------------
// k_gemm2: z[pg][o][v] = GN1( Wf @ [y|y'] ) fp64, one t-chunk.
// 512 thr = 4 groups x 128 o; 4 pairs/group. Wf f32 in 128KB LDS.
// ---------------------------------------------------------------------------
__global__ __launch_bounds__(512) void k_gemm2(
    const double* __restrict__ y_buf, const float* __restrict__ WfT,
    const float* __restrict__ fg, const float* __restrict__ fb,
    double* __restrict__ z_out, int chunk_base)
{
  __shared__ float wft[32768];                 // [c2][o], 128 KB
  __shared__ double red[4][4][2][2];           // [grp][k][stat][wave]
  const int tid  = threadIdx.x;
  const int o    = tid & 127;
  const int grp  = tid >> 7;
  const int wv   = (tid >> 6) & 1;
  const int lane = tid & 63;
  const int pl0  = blockIdx.x * 16 + grp * 4;

  for (int i = tid; i < 32768; i += 512) wft[i] = WfT[i];
  __syncthreads();

  int yb[4];
#pragma unroll
  for (int k = 0; k < 4; ++k)
    yb[k] = __builtin_amdgcn_readfirstlane((pl0 + k) * XROW);

  double acc[4][5];
#pragma unroll
  for (int k = 0; k < 4; ++k)
#pragma unroll
    for (int v = 0; v < 5; ++v) acc[k][v] = 0.0;

#pragma unroll 2
  for (int c2 = 0; c2 < 256; ++c2) {
    const double w = (double)wft[(c2 << 7) + o];
    const int yoff = (c2 & 127) * 10 + (c2 >> 7) * 5;
#pragma unroll
    for (int k = 0; k < 4; ++k) {
      const double* yp = y_buf + yb[k] + yoff;
#pragma unroll
      for (int v = 0; v < 5; ++v)
        acc[k][v] = fma(w, yp[v], acc[k][v]);
    }
  }

  // GN1 over 640 per pair (2 waves per group)
  double mu[4];
#pragma unroll
  for (int k = 0; k < 4; ++k) {
    double s = acc[k][0] + acc[k][1] + acc[k][2] + acc[k][3] + acc[k][4];
#pragma unroll
    for (int off = 1; off < 64; off <<= 1) s += __shfl_xor(s, off, 64);
    if (lane == 0) red[grp][k][0][wv] = s;
  }
  __syncthreads();
#pragma unroll
  for (int k = 0; k < 4; ++k)
    mu[k] = (red[grp][k][0][0] + red[grp][k][0][1]) * (1.0 / 640.0);
#pragma unroll
  for (int k = 0; k < 4; ++k) {
    double q = 0.0;
#pragma unroll
    for (int v = 0; v < 5; ++v) { double d = acc[k][v] - mu[k]; q = fma(d, d, q); }
#pragma unroll
    for (int off = 1; off < 64; off <<= 1) q += __shfl_xor(q, off, 64);
    if (lane == 0) red[grp][k][1][wv] = q;
  }
  __syncthreads();
  const double gam = (double)fg[o], bet = (double)fb[o];
#pragma unroll
  for (int k = 0; k < 4; ++k) {
    const double rstd =
        1.0 / sqrt((red[grp][k][1][0] + red[grp][k][1][1]) * (1.0 / 640.0) + 1e-5);
    double* zo = z_out + (size_t)(chunk_base + pl0 + k) * ZROW + o * 5;
#pragma unroll
    for (int v = 0; v < 5; ++v)
      zo[v] = (acc[k][v] - mu[k]) * rstd * gam + bet;
  }
}

// ---------------------------------------------------------------------------
// k_temporal: LIF1 -> 5x5 mix -> GN(V,T) -> LIF2 -> EMA gate -> dyn LIF -> out
// fp64 state; m overwrites z in place; fused sum+sumsq; next-t prefetch.
// ---------------------------------------------------------------------------
__global__ __launch_bounds__(256) void k_temporal(
    const float* __restrict__ x, double* __restrict__ zm,
    const float* __restrict__ la, const float* __restrict__ nm,
    const float* __restrict__ adj, const float* __restrict__ mg,
    const float* __restrict__ mb, float* __restrict__ out)
{
  const int gid = blockIdx.x * 256 + threadIdx.x;
  const int bc = gid >> 3;
  const int u  = gid & 7;
  const bool act = (u < 5);

  double w[5];
#pragma unroll
  for (int v = 0; v < 5; ++v) {
    if (act) {
      double sa = 0.5 * ((double)adj[u * 5 + v] + (double)adj[v * 5 + u]);
      w[v] = (double)nm[u * 5 + v] * (1.0 / (1.0 + exp(-sa)));
    } else {
      w[v] = 0.0;
    }
  }
  const double aa  = 1.0 / (1.0 + exp(-(double)la[0]));
  const double oma = 1.0 - aa;
  const int lane  = threadIdx.x & 63;
  const int gbase = lane & ~7;
  const size_t zoff = (size_t)bc * 5 + u;

  double v1 = 0.0, ssum = 0.0, ssq = 0.0;
  double znext = act ? zm[zoff] : 0.0;
  for (int t = 0; t < T_; ++t) {
    const double zc = znext;
    if (t < T_ - 1)
      znext = act ? zm[zoff + (size_t)(t + 1) * ZSTRIDE] : 0.0;
    v1 = v1 + (zc - v1) * 0.5;
    double sp = (v1 - 0.8 >= 0.0) ? 1.0 : 0.0;
    v1 *= (1.0 - sp);
    double m = 0.0;
#pragma unroll
    for (int v = 0; v < 5; ++v) m = fma(w[v], __shfl(sp, gbase + v, 64), m);
    ssum += m;
    ssq = fma(m, m, ssq);
    if (act) zm[zoff + (size_t)t * ZSTRIDE] = m;
  }
#pragma unroll
  for (int off = 1; off < 8; off <<= 1) {
    ssum += __shfl_xor(ssum, off, 64);
    ssq  += __shfl_xor(ssq,  off, 64);
  }
  const double mu = ssum * (1.0 / 640.0);
  double var = ssq * (1.0 / 640.0) - mu * mu;
  const double rstd = 1.0 / sqrt(var + 1e-5);
  const double gam = act ? (double)mg[u] : 0.0;
  const double bet = act ? (double)mb[u] : 0.0;

  double v2 = 0.0, e0 = 0.0, e1 = 0.0, dd0 = 0.0, dd1 = 0.0;
  const size_t xoff = (size_t)bc * 10;
  double mnext = act ? zm[zoff] : 0.0;
  float x0n = act ? x[xoff + u] : 0.f;
  float x1n = act ? x[xoff + u + 5] : 0.f;
  for (int t = 0; t < T_; ++t) {
    const double mval = mnext;
    const float x0f = x0n, x1f = x1n;
    if (t < T_ - 1) {
      mnext = act ? zm[zoff + (size_t)(t + 1) * ZSTRIDE] : 0.0;
      x0n = act ? x[(size_t)(t + 1) * XSTRIDE + xoff + u] : 0.f;
      x1n = act ? x[(size_t)(t + 1) * XSTRIDE + xoff + u + 5] : 0.f;
    }
    double mn = (mval - mu) * rstd * gam + bet;
    v2 = v2 + (mn - v2) * 0.5;
    double s2 = (v2 - 0.8 >= 0.0) ? 1.0 : 0.0;
    v2 *= (1.0 - s2);

    e0 = e0 * aa + (double)x0f * oma;
    e1 = e1 * aa + (double)x1f * oma;

    dd0 = dd0 * 0.8 + s2;
    double sd0 = (dd0 - 0.8 * (2.0 - e0) >= 0.0) ? 1.0 : 0.0;
    dd0 *= (1.0 - sd0);

    dd1 = dd1 * 0.8 + s2;
    double sd1 = (dd1 - 0.8 * (2.0 - e1) >= 0.0) ? 1.0 : 0.0;
    dd1 *= (1.0 - sd1);

    if (act) {
      out[(size_t)t * XSTRIDE + xoff + u] =
          fminf(fmaxf(x0f + (float)sd0, 0.f), 1.f);
      out[(size_t)t * XSTRIDE + xoff + u + 5] =
          fminf(fmaxf(x1f + (float)sd1, 0.f), 1.f);
    }
  }
}

// ---------------------------------------------------------------------------
extern "C" void kernel_launch(void* const* d_in, const int* in_sizes, int n_in,
                              void* d_out, int out_size, void* d_ws, size_t ws_size,
                              hipStream_t stream) {
  const float* x   = (const float*)d_in[0];
  const float* W1  = (const float*)d_in[1];
  const float* g1  = (const float*)d_in[2];
  const float* b1  = (const float*)d_in[3];
  const float* la  = (const float*)d_in[4];
  const float* Wf  = (const float*)d_in[5];
  const float* fg  = (const float*)d_in[6];
  const float* fb  = (const float*)d_in[7];
  const float* nm  = (const float*)d_in[8];
  const float* adj = (const float*)d_in[9];
  const float* mg  = (const float*)d_in[10];
  const float* mb  = (const float*)d_in[11];
  float* outp = (float*)d_out;

  // ws layout: z (84MB) | y_buf (PQ*10240B) | x_d (PQ*10240B) | W1T 64KB | WfT 128KB
  const size_t zB = 83886080ull;
  const size_t need32 = zB + 2ull * 41943040 + 196608;   // ~168 MB
  const int nChunks = (ws_size >= need32) ? 4 : 8;
  const int PQ = 16384 / nChunks;                        // pairs per chunk
  const size_t pqB = (size_t)PQ * XROW * sizeof(double);

  double* z_ws  = (double*)d_ws;
  double* y_buf = (double*)((char*)d_ws + zB);
  double* x_d   = (double*)((char*)d_ws + zB + pqB);
  float*  W1T   = (float*)((char*)d_ws + zB + 2 * pqB);
  float*  WfT   = (float*)((char*)d_ws + zB + 2 * pqB + 65536);

  hipLaunchKernelGGL(k_prep, dim3(192), dim3(256), 0, stream, W1, Wf, W1T, WfT);
  for (int q = 0; q < nChunks; ++q) {
    const int cb = q * PQ;
    hipLaunchKernelGGL(k_xconv, dim3(PQ * 640 / 256), dim3(256), 0, stream,
                       x, x_d, (long long)cb * XROW);
    hipLaunchKernelGGL(k_gemm1, dim3(PQ / 16), dim3(512), 0, stream,
                       x_d, W1T, g1, b1, y_buf);
    hipLaunchKernelGGL(k_gemm2, dim3(PQ / 16), dim3(512), 0, stream,
                       y_buf, WfT, fg, fb, z_ws, cb);
  }
  hipLaunchKernelGGL(k_temporal, dim3(512), dim3(256), 0, stream,
                     x, z_ws, la, nm, adj, mg, mb, outp);
}